// Round 2
// baseline (1362.966 us; speedup 1.0000x reference)
//
#include <hip/hip_runtime.h>
#include <math.h>

// EqualityConstraint: x_new = x - J^T G^{-1} F(x)
//   t = tanh(x); s = 1 - t^2; J = A diag(s)
//   F = A t + p; G = A diag(s^2) A^T  (SPD, M x M)
//   y = G^{-1} F;  x_new = x - s .* (A^T y)
//
// One 256-thread block per batch row. Threads form a 16x16 grid (ti=row tile,
// tk=col tile); each owns an 8x8 register tile of G which becomes its tile of
// L after an in-register blocked right-looking Cholesky. Only the current
// 8-column panel lives in LDS (4.2 KB), so total LDS ~18.5 KB -> 4 blocks/CU
// (VGPR-limited at 128) instead of the 2 the old 80 KB footprint allowed.
// Triangular solves are distributed block solves over the register tiles.

#define kN 256   // x dim
#define kM 128   // constraint dim
#define STP 132  // stage row pitch (floats), 16B-aligned rows
#define PP  132  // panel row pitch
#define RP  8    // reduction-slot pitch

__global__ __launch_bounds__(256, 4)
void eqcon_kernel(const float* __restrict__ x,
                  const float* __restrict__ parms,
                  const float* __restrict__ A,
                  float* __restrict__ out)
{
    __shared__ float t_s[kN];
    __shared__ float s_s[kN];
    __shared__ float Fx_s[kM];
    __shared__ float z_s[kM];
    __shared__ float y_s[kM];
    __shared__ float invd_s[kM];
    __shared__ float Ld_s[64];
    __shared__ float stage[16 * STP];   // stage[jj][i] = A[i][jt+jj]
    __shared__ float panel_s[8 * PP];   // panel_s[c][i] = L[i][kb+c], current panel
    __shared__ float red_s[16 * RP];    // block-solve reduction slots

    const int tid = (int)threadIdx.x;
    const int b   = (int)blockIdx.x;
    const int ti  = tid & 15;   // row-tile index
    const int tk  = tid >> 4;   // col-tile index

    // ---- Phase 1: t = tanh(x), s = sech^2(x) ----
    const float xv = x[b * kN + tid];
    const float tv = tanhf(xv);
    const float sv = 1.0f - tv * tv;
    t_s[tid] = tv;
    s_s[tid] = sv;
    __syncthreads();

    // ---- Phase 2: Fx = A t + parms (2 threads per row) ----
    {
        const int row  = tid >> 1;
        const int half = tid & 1;
        const float4* __restrict__ Ar =
            reinterpret_cast<const float4*>(A + row * kN + half * (kN / 2));
        const float4* Tr = reinterpret_cast<const float4*>(t_s + half * (kN / 2));
        float sum = 0.0f;
#pragma unroll
        for (int q = 0; q < kN / 8; ++q) {
            const float4 a4 = Ar[q];
            const float4 t4 = Tr[q];
            sum += a4.x * t4.x + a4.y * t4.y + a4.z * t4.z + a4.w * t4.w;
        }
        sum += __shfl_xor(sum, 1);
        if (half == 0) Fx_s[row] = sum + parms[b * kM + row];
    }

    // ---- Phase 3: G = A diag(s^2) A^T, each thread an 8x8 register tile ----
    float acc[8][8];
#pragma unroll
    for (int r = 0; r < 8; ++r)
#pragma unroll
        for (int c = 0; c < 8; ++c) acc[r][c] = 0.0f;

#pragma unroll 1
    for (int jt = 0; jt < kN; jt += 16) {
        __syncthreads();  // prev tile's compute done before overwriting stage
#pragma unroll
        for (int rep = 0; rep < 8; ++rep) {
            const int idx = rep * 256 + tid;
            const int i   = idx >> 4;
            const int jj  = idx & 15;
            stage[jj * STP + i] = A[i * kN + (jt + jj)];
        }
        __syncthreads();
#pragma unroll
        for (int jj = 0; jj < 16; ++jj) {
            const float sj = s_s[jt + jj];
            const float w  = sj * sj;
            const float* rowp = stage + jj * STP;
            const float4 a0 = *reinterpret_cast<const float4*>(rowp + ti * 8);
            const float4 a1 = *reinterpret_cast<const float4*>(rowp + ti * 8 + 4);
            const float4 b0 = *reinterpret_cast<const float4*>(rowp + tk * 8);
            const float4 b1 = *reinterpret_cast<const float4*>(rowp + tk * 8 + 4);
            const float av[8] = {a0.x, a0.y, a0.z, a0.w, a1.x, a1.y, a1.z, a1.w};
            const float bv[8] = {b0.x * w, b0.y * w, b0.z * w, b0.w * w,
                                 b1.x * w, b1.y * w, b1.z * w, b1.w * w};
#pragma unroll
            for (int r = 0; r < 8; ++r)
#pragma unroll
                for (int c = 0; c < 8; ++c) acc[r][c] += av[r] * bv[c];
        }
    }
    __syncthreads();

    // ---- Phase 4: in-register blocked Cholesky (8-col panels) ----
    // After this, thread (ti,tk) with ti>=tk holds L tile (ti,tk) in acc.
#pragma unroll 1
    for (int pb = 0; pb < 16; ++pb) {
        const int kb = pb * 8;
        if (ti == pb && tk == pb) {
            // 8x8 diagonal Cholesky in registers (lower triangle)
#pragma unroll
            for (int kk = 0; kk < 8; ++kk) {
                float d = fmaxf(acc[kk][kk], 1e-30f);
                const float rd  = sqrtf(d);
                const float inv = 1.0f / rd;
                invd_s[kb + kk] = inv;
                acc[kk][kk] = rd;
#pragma unroll
                for (int r = kk + 1; r < 8; ++r) acc[r][kk] *= inv;
#pragma unroll
                for (int r = kk + 1; r < 8; ++r)
#pragma unroll
                    for (int c = kk + 1; c <= r; ++c)
                        acc[r][c] -= acc[r][kk] * acc[c][kk];
            }
#pragma unroll
            for (int r = 0; r < 8; ++r)
#pragma unroll
                for (int c = 0; c < 8; ++c) Ld_s[r * 8 + c] = acc[r][c];
        }
        __syncthreads();
        if (tk == pb && ti > pb) {
            // panel solve: B := B * Ld^{-T}; result is final L tile (ti,pb)
#pragma unroll
            for (int c = 0; c < 8; ++c) {
#pragma unroll
                for (int m = 0; m < 8; ++m) {
                    if (m < c) {
                        const float coef = Ld_s[c * 8 + m];
#pragma unroll
                        for (int r = 0; r < 8; ++r) acc[r][c] -= acc[r][m] * coef;
                    }
                }
                const float inv = invd_s[kb + c];
#pragma unroll
                for (int r = 0; r < 8; ++r) acc[r][c] *= inv;
            }
            // publish panel for trailing update: panel_s[c][i] = L[i][kb+c]
#pragma unroll
            for (int c = 0; c < 8; ++c)
#pragma unroll
                for (int r = 0; r < 8; ++r) panel_s[c * PP + ti * 8 + r] = acc[r][c];
        }
        __syncthreads();
        if (ti > pb && tk > pb) {
            // rank-8 trailing update from the freshly written panel
#pragma unroll
            for (int m = 0; m < 8; ++m) {
                const float* lr = panel_s + m * PP;
                const float4 c0 = *reinterpret_cast<const float4*>(lr + ti * 8);
                const float4 c1 = *reinterpret_cast<const float4*>(lr + ti * 8 + 4);
                const float4 d0 = *reinterpret_cast<const float4*>(lr + tk * 8);
                const float4 d1 = *reinterpret_cast<const float4*>(lr + tk * 8 + 4);
                const float cl[8] = {c0.x, c0.y, c0.z, c0.w, c1.x, c1.y, c1.z, c1.w};
                const float cc[8] = {d0.x, d0.y, d0.z, d0.w, d1.x, d1.y, d1.z, d1.w};
#pragma unroll
                for (int r = 0; r < 8; ++r)
#pragma unroll
                    for (int c = 0; c < 8; ++c) acc[r][c] -= cl[r] * cc[c];
            }
        }
        // no barrier needed: post-diag barrier next iter orders panel_s reuse
    }
    __syncthreads();

    // ---- Phase 5a: forward block solve L z = Fx (distributed tiles) ----
#pragma unroll 1
    for (int I = 0; I < 16; ++I) {
        if (ti == I && tk < I) {
            // u = L(I,tk) * z[tk-block]
            float u[8];
#pragma unroll
            for (int r = 0; r < 8; ++r) u[r] = 0.0f;
#pragma unroll
            for (int c = 0; c < 8; ++c) {
                const float zc = z_s[tk * 8 + c];
#pragma unroll
                for (int r = 0; r < 8; ++r) u[r] += acc[r][c] * zc;
            }
#pragma unroll
            for (int r = 0; r < 8; ++r) red_s[tk * RP + r] = u[r];
        }
        __syncthreads();
        if (ti == I && tk == I) {
            float w[8];
#pragma unroll
            for (int r = 0; r < 8; ++r) w[r] = Fx_s[I * 8 + r];
            for (int K = 0; K < I; ++K)
#pragma unroll
                for (int r = 0; r < 8; ++r) w[r] -= red_s[K * RP + r];
            float zl[8];
#pragma unroll
            for (int r = 0; r < 8; ++r) {
                float v = w[r];
#pragma unroll
                for (int m = 0; m < 8; ++m)
                    if (m < r) v -= acc[r][m] * zl[m];
                zl[r] = v * invd_s[I * 8 + r];
                z_s[I * 8 + r] = zl[r];
            }
        }
        __syncthreads();
    }

    // ---- Phase 5b: backward block solve L^T y = z ----
#pragma unroll 1
    for (int K = 15; K >= 0; --K) {
        if (tk == K && ti > K) {
            // u = L(ti,K)^T * y[ti-block]
            float u[8];
#pragma unroll
            for (int c = 0; c < 8; ++c) u[c] = 0.0f;
#pragma unroll
            for (int r = 0; r < 8; ++r) {
                const float yr = y_s[ti * 8 + r];
#pragma unroll
                for (int c = 0; c < 8; ++c) u[c] += acc[r][c] * yr;
            }
#pragma unroll
            for (int c = 0; c < 8; ++c) red_s[ti * RP + c] = u[c];
        }
        __syncthreads();
        if (ti == K && tk == K) {
            float w[8];
#pragma unroll
            for (int c = 0; c < 8; ++c) w[c] = z_s[K * 8 + c];
            for (int I = K + 1; I < 16; ++I)
#pragma unroll
                for (int c = 0; c < 8; ++c) w[c] -= red_s[I * RP + c];
            float yl[8];
#pragma unroll
            for (int cc = 0; cc < 8; ++cc) {
                const int c = 7 - cc;
                float v = w[c];
#pragma unroll
                for (int m = 0; m < 8; ++m)
                    if (m > c) v -= acc[m][c] * yl[m];
                yl[c] = v * invd_s[K * 8 + c];
                y_s[K * 8 + c] = yl[c];
            }
        }
        __syncthreads();
    }

    // ---- Phase 6: x_new = x - s .* (A^T y) (coalesced over columns) ----
    {
        float sum = 0.0f;
#pragma unroll 8
        for (int i = 0; i < kM; ++i) sum += A[i * kN + tid] * y_s[i];
        out[b * kN + tid] = xv - sv * sum;
    }
}

extern "C" void kernel_launch(void* const* d_in, const int* in_sizes, int n_in,
                              void* d_out, int out_size, void* d_ws, size_t ws_size,
                              hipStream_t stream) {
    const float* x     = (const float*)d_in[0];
    const float* parms = (const float*)d_in[1];
    const float* A     = (const float*)d_in[2];
    float* out = (float*)d_out;
    const int Bcount = in_sizes[0] / kN;  // 2048
    eqcon_kernel<<<dim3(Bcount), dim3(256), 0, stream>>>(x, parms, A, out);
}

// Round 3
// 1020.771 us; speedup vs baseline: 1.3352x; 1.3352x over previous
//
#include <hip/hip_runtime.h>
#include <math.h>

// EqualityConstraint: x_new = x - J^T G^{-1} F(x)
//   t = tanh(x); s = 1 - t^2; J = A diag(s)
//   F = A t + p; G = A diag(s^2) A^T  (SPD, M x M)
//   y = G^{-1} F;  x_new = x - s .* (A^T y)
//
// One 256-thread block per batch row. Threads form a 16x16 grid (ti=row tile,
// tk=col tile); each owns an 8x8 register tile of G which becomes its tile of
// L after an in-register blocked right-looking Cholesky. Only the current
// 8-column panel lives in LDS; total LDS ~18 KB.
//
// __launch_bounds__(256,3): VGPR cap 170. R2 post-mortem: bound 4 (cap 128)
// forced a catastrophic spill of acc (VGPR 64, 5.1 GB scratch traffic,
// 870->1460 us). Natural pressure is ~110-130; 3 blocks/CU is the highest
// occupancy with no-spill headroom.

#define kN 256   // x dim
#define kM 128   // constraint dim
#define STP 132  // stage row pitch (floats), 16B-aligned rows
#define PP  132  // panel row pitch
#define RP  8    // reduction-slot pitch

__global__ __launch_bounds__(256, 3)
void eqcon_kernel(const float* __restrict__ x,
                  const float* __restrict__ parms,
                  const float* __restrict__ A,
                  float* __restrict__ out)
{
    __shared__ float t_s[kN];
    __shared__ float s_s[kN];
    __shared__ float Fx_s[kM];
    __shared__ float z_s[kM];
    __shared__ float y_s[kM];
    __shared__ float invd_s[kM];
    __shared__ float Ld_s[64];
    __shared__ float stage[16 * STP];   // stage[jj][i] = A[i][jt+jj]
    __shared__ float panel_s[8 * PP];   // panel_s[c][i] = L[i][kb+c], current panel
    __shared__ float red_s[16 * RP];    // block-solve reduction slots

    const int tid = (int)threadIdx.x;
    const int b   = (int)blockIdx.x;
    const int ti  = tid & 15;   // row-tile index
    const int tk  = tid >> 4;   // col-tile index

    // ---- Phase 1: t = tanh(x), s = sech^2(x) ----
    const float xv = x[b * kN + tid];
    const float tv = tanhf(xv);
    const float sv = 1.0f - tv * tv;
    t_s[tid] = tv;
    s_s[tid] = sv;
    __syncthreads();

    // ---- Phase 2: Fx = A t + parms (2 threads per row) ----
    {
        const int row  = tid >> 1;
        const int half = tid & 1;
        const float4* __restrict__ Ar =
            reinterpret_cast<const float4*>(A + row * kN + half * (kN / 2));
        const float4* Tr = reinterpret_cast<const float4*>(t_s + half * (kN / 2));
        float sum = 0.0f;
#pragma unroll
        for (int q = 0; q < kN / 8; ++q) {
            const float4 a4 = Ar[q];
            const float4 t4 = Tr[q];
            sum += a4.x * t4.x + a4.y * t4.y + a4.z * t4.z + a4.w * t4.w;
        }
        sum += __shfl_xor(sum, 1);
        if (half == 0) Fx_s[row] = sum + parms[b * kM + row];
    }

    // ---- Phase 3: G = A diag(s^2) A^T, each thread an 8x8 register tile ----
    float acc[8][8];
#pragma unroll
    for (int r = 0; r < 8; ++r)
#pragma unroll
        for (int c = 0; c < 8; ++c) acc[r][c] = 0.0f;

#pragma unroll 1
    for (int jt = 0; jt < kN; jt += 16) {
        __syncthreads();  // prev tile's compute done before overwriting stage
#pragma unroll
        for (int rep = 0; rep < 8; ++rep) {
            const int idx = rep * 256 + tid;
            const int i   = idx >> 4;
            const int jj  = idx & 15;
            stage[jj * STP + i] = A[i * kN + (jt + jj)];
        }
        __syncthreads();
#pragma unroll
        for (int jj = 0; jj < 16; ++jj) {
            const float sj = s_s[jt + jj];
            const float w  = sj * sj;
            const float* rowp = stage + jj * STP;
            const float4 a0 = *reinterpret_cast<const float4*>(rowp + ti * 8);
            const float4 a1 = *reinterpret_cast<const float4*>(rowp + ti * 8 + 4);
            const float4 b0 = *reinterpret_cast<const float4*>(rowp + tk * 8);
            const float4 b1 = *reinterpret_cast<const float4*>(rowp + tk * 8 + 4);
            // fold w into the row operand (one side only)
            const float av[8] = {a0.x * w, a0.y * w, a0.z * w, a0.w * w,
                                 a1.x * w, a1.y * w, a1.z * w, a1.w * w};
            const float bv[8] = {b0.x, b0.y, b0.z, b0.w, b1.x, b1.y, b1.z, b1.w};
#pragma unroll
            for (int r = 0; r < 8; ++r)
#pragma unroll
                for (int c = 0; c < 8; ++c) acc[r][c] += av[r] * bv[c];
        }
    }
    __syncthreads();

    // ---- Phase 4: in-register blocked Cholesky (8-col panels) ----
    // After this, thread (ti,tk) with ti>=tk holds L tile (ti,tk) in acc.
#pragma unroll 1
    for (int pb = 0; pb < 16; ++pb) {
        const int kb = pb * 8;
        if (ti == pb && tk == pb) {
            // 8x8 diagonal Cholesky in registers (lower triangle)
#pragma unroll
            for (int kk = 0; kk < 8; ++kk) {
                float d = fmaxf(acc[kk][kk], 1e-30f);
                const float rd  = sqrtf(d);
                const float inv = 1.0f / rd;
                invd_s[kb + kk] = inv;
                acc[kk][kk] = rd;
#pragma unroll
                for (int r = kk + 1; r < 8; ++r) acc[r][kk] *= inv;
#pragma unroll
                for (int r = kk + 1; r < 8; ++r)
#pragma unroll
                    for (int c = kk + 1; c <= r; ++c)
                        acc[r][c] -= acc[r][kk] * acc[c][kk];
            }
#pragma unroll
            for (int r = 0; r < 8; ++r)
#pragma unroll
                for (int c = 0; c < 8; ++c) Ld_s[r * 8 + c] = acc[r][c];
        }
        __syncthreads();
        if (tk == pb && ti > pb) {
            // panel solve: B := B * Ld^{-T}; result is final L tile (ti,pb)
#pragma unroll
            for (int c = 0; c < 8; ++c) {
#pragma unroll
                for (int m = 0; m < 8; ++m) {
                    if (m < c) {
                        const float coef = Ld_s[c * 8 + m];
#pragma unroll
                        for (int r = 0; r < 8; ++r) acc[r][c] -= acc[r][m] * coef;
                    }
                }
                const float inv = invd_s[kb + c];
#pragma unroll
                for (int r = 0; r < 8; ++r) acc[r][c] *= inv;
            }
            // publish panel for trailing update: panel_s[c][i] = L[i][kb+c]
#pragma unroll
            for (int c = 0; c < 8; ++c)
#pragma unroll
                for (int r = 0; r < 8; ++r) panel_s[c * PP + ti * 8 + r] = acc[r][c];
        }
        __syncthreads();
        if (ti > pb && tk > pb) {
            // rank-8 trailing update from the freshly written panel
#pragma unroll
            for (int m = 0; m < 8; ++m) {
                const float* lr = panel_s + m * PP;
                const float4 c0 = *reinterpret_cast<const float4*>(lr + ti * 8);
                const float4 c1 = *reinterpret_cast<const float4*>(lr + ti * 8 + 4);
                const float4 d0 = *reinterpret_cast<const float4*>(lr + tk * 8);
                const float4 d1 = *reinterpret_cast<const float4*>(lr + tk * 8 + 4);
                const float cl[8] = {c0.x, c0.y, c0.z, c0.w, c1.x, c1.y, c1.z, c1.w};
                const float cc[8] = {d0.x, d0.y, d0.z, d0.w, d1.x, d1.y, d1.z, d1.w};
#pragma unroll
                for (int r = 0; r < 8; ++r)
#pragma unroll
                    for (int c = 0; c < 8; ++c) acc[r][c] -= cl[r] * cc[c];
            }
        }
        // no barrier needed: post-diag barrier next iter orders panel_s reuse
    }
    __syncthreads();

    // ---- Phase 5a: forward block solve L z = Fx (distributed tiles) ----
#pragma unroll 1
    for (int I = 0; I < 16; ++I) {
        if (ti == I && tk < I) {
            // u = L(I,tk) * z[tk-block]
            float u[8];
#pragma unroll
            for (int r = 0; r < 8; ++r) u[r] = 0.0f;
#pragma unroll
            for (int c = 0; c < 8; ++c) {
                const float zc = z_s[tk * 8 + c];
#pragma unroll
                for (int r = 0; r < 8; ++r) u[r] += acc[r][c] * zc;
            }
#pragma unroll
            for (int r = 0; r < 8; ++r) red_s[tk * RP + r] = u[r];
        }
        __syncthreads();
        if (ti == I && tk == I) {
            float w[8];
#pragma unroll
            for (int r = 0; r < 8; ++r) w[r] = Fx_s[I * 8 + r];
            for (int K = 0; K < I; ++K)
#pragma unroll
                for (int r = 0; r < 8; ++r) w[r] -= red_s[K * RP + r];
            float zl[8];
#pragma unroll
            for (int r = 0; r < 8; ++r) {
                float v = w[r];
#pragma unroll
                for (int m = 0; m < 8; ++m)
                    if (m < r) v -= acc[r][m] * zl[m];
                zl[r] = v * invd_s[I * 8 + r];
                z_s[I * 8 + r] = zl[r];
            }
        }
        __syncthreads();
    }

    // ---- Phase 5b: backward block solve L^T y = z ----
#pragma unroll 1
    for (int K = 15; K >= 0; --K) {
        if (tk == K && ti > K) {
            // u = L(ti,K)^T * y[ti-block]
            float u[8];
#pragma unroll
            for (int c = 0; c < 8; ++c) u[c] = 0.0f;
#pragma unroll
            for (int r = 0; r < 8; ++r) {
                const float yr = y_s[ti * 8 + r];
#pragma unroll
                for (int c = 0; c < 8; ++c) u[c] += acc[r][c] * yr;
            }
#pragma unroll
            for (int c = 0; c < 8; ++c) red_s[ti * RP + c] = u[c];
        }
        __syncthreads();
        if (ti == K && tk == K) {
            float w[8];
#pragma unroll
            for (int c = 0; c < 8; ++c) w[c] = z_s[K * 8 + c];
            for (int I = K + 1; I < 16; ++I)
#pragma unroll
                for (int c = 0; c < 8; ++c) w[c] -= red_s[I * RP + c];
            float yl[8];
#pragma unroll
            for (int cc = 0; cc < 8; ++cc) {
                const int c = 7 - cc;
                float v = w[c];
#pragma unroll
                for (int m = 0; m < 8; ++m)
                    if (m > c) v -= acc[m][c] * yl[m];
                yl[c] = v * invd_s[K * 8 + c];
                y_s[K * 8 + c] = yl[c];
            }
        }
        __syncthreads();
    }

    // ---- Phase 6: x_new = x - s .* (A^T y) (coalesced over columns) ----
    {
        float sum = 0.0f;
#pragma unroll 8
        for (int i = 0; i < kM; ++i) sum += A[i * kN + tid] * y_s[i];
        out[b * kN + tid] = xv - sv * sum;
    }
}

extern "C" void kernel_launch(void* const* d_in, const int* in_sizes, int n_in,
                              void* d_out, int out_size, void* d_ws, size_t ws_size,
                              hipStream_t stream) {
    const float* x     = (const float*)d_in[0];
    const float* parms = (const float*)d_in[1];
    const float* A     = (const float*)d_in[2];
    float* out = (float*)d_out;
    const int Bcount = in_sizes[0] / kN;  // 2048
    eqcon_kernel<<<dim3(Bcount), dim3(256), 0, stream>>>(x, parms, A, out);
}